// Round 2
// baseline (346.384 us; speedup 1.0000x reference)
//
#include <hip/hip_runtime.h>

#define H 512
#define NNODES 10000
#define NEDGES 160000
#define NLAYERS 5

typedef __attribute__((ext_vector_type(8))) short short8;
typedef __attribute__((ext_vector_type(4))) float floatx4;
typedef __attribute__((ext_vector_type(2))) float floatx2;

// ---------- helpers ----------
__device__ inline unsigned short f2bf(float v) {
    union { float f; unsigned int u; } x; x.f = v;
    unsigned int r = (x.u + 0x7fffu + ((x.u >> 16) & 1u)) >> 16;
    return (unsigned short)r;
}
__device__ inline float bf2f(unsigned short u) {
    union { unsigned int u; float f; } x; x.u = ((unsigned int)u) << 16; return x.f;
}
__device__ inline void gl_lds16(const void* g, void* l) {
    __builtin_amdgcn_global_load_lds((const __attribute__((address_space(1))) void*)g,
                                     (__attribute__((address_space(3))) void*)l, 16, 0, 0);
}

// ---------- prep kernels ----------
__global__ void zero_int(int* __restrict__ p, int n) {
    int i = blockIdx.x * blockDim.x + threadIdx.x;
    if (i < n) p[i] = 0;
}

__global__ void cvt_f32_bf16(const float* __restrict__ in, unsigned short* __restrict__ out, int n4) {
    int i = blockIdx.x * blockDim.x + threadIdx.x;
    if (i < n4) {
        float4 v = ((const float4*)in)[i];
        ushort4 o;
        o.x = f2bf(v.x); o.y = f2bf(v.y); o.z = f2bf(v.z); o.w = f2bf(v.w);
        ((ushort4*)out)[i] = o;
    }
}

// batched: z in [0,6): 5 layer weights + vw1. out[n][k] = in[k][n], bf16
__global__ void transpose_cvt6(const float* __restrict__ Wg, const float* __restrict__ vw1,
                               unsigned short* __restrict__ Wt) {
    __shared__ float tile[32][33];
    const int z = blockIdx.z;
    const float* in = (z < NLAYERS) ? (Wg + (size_t)z * H * H) : vw1;
    unsigned short* out = Wt + (size_t)z * H * H;
    const int bx = blockIdx.x * 32;
    const int by = blockIdx.y * 32;
    const int tx = threadIdx.x, ty = threadIdx.y;  // (32,8)
    for (int i = ty; i < 32; i += 8)
        tile[i][tx] = in[(size_t)(by + i) * H + bx + tx];
    __syncthreads();
    for (int i = ty; i < 32; i += 8)
        out[(size_t)(bx + i) * H + by + tx] = f2bf(tile[tx][i]);
}

__global__ void edge_hist(const int* __restrict__ rows, int* __restrict__ counts, int n) {
    int i = blockIdx.x * blockDim.x + threadIdx.x;
    if (i < n) atomicAdd(&counts[rows[i]], 1);
}

// prefix-sum of row counts PADDED to multiples of 8 (dummy edges have val=0
// -> exact no-ops in the accumulation; enables branch-free SpMM rounds)
__global__ __launch_bounds__(1024)
void scan_rows_pad(const int* __restrict__ counts, int* __restrict__ row_ptr, int n) {
    __shared__ int sums[1024];
    const int t = threadIdx.x;
    const int base = t * 16;
    int local[16];
    int s = 0;
#pragma unroll
    for (int i = 0; i < 16; ++i) {
        int idx = base + i;
        int v = (idx < n) ? ((counts[idx] + 7) & ~7) : 0;
        local[i] = s;
        s += v;
    }
    sums[t] = s;
    __syncthreads();
    for (int off = 1; off < 1024; off <<= 1) {
        int v = (t >= off) ? sums[t - off] : 0;
        __syncthreads();
        sums[t] += v;
        __syncthreads();
    }
    const int prefix = (t == 0) ? 0 : sums[t - 1];
#pragma unroll
    for (int i = 0; i < 16; ++i) {
        int idx = base + i;
        if (idx < n) row_ptr[idx] = prefix + local[i];
    }
    if (t == 0) row_ptr[n] = sums[1023];
}

__global__ void edge_scatter(const int* __restrict__ rows, const int* __restrict__ colsin,
                             const float* __restrict__ valsin, const int* __restrict__ row_ptr,
                             int* __restrict__ fill, int* __restrict__ colsout,
                             float* __restrict__ valsout, int n) {
    int i = blockIdx.x * blockDim.x + threadIdx.x;
    if (i < n) {
        int r = rows[i];
        int pos = row_ptr[r] + atomicAdd(&fill[r], 1);
        colsout[pos] = colsin[i];
        valsout[pos] = valsin[i];
    }
}

// ---------- GEMM body (128x64, BK=64, XOR k-slot swizzle, 3-STAGE RING) ----------
// r1 change: 3 LDS buffers + counted vmcnt. At the end of iter `it` we wait
// vmcnt(6): that targets stage(it+1), ISSUED ONE FULL ITERATION AGO (~300+cy),
// while stage(it+2)'s 6 loads stay in flight across the raw s_barrier.
// The 2-buffer r0 version still had to drain the stage issued the SAME iter
// -> exposed latency. K order unchanged -> numerics bit-identical.
// Hazard proof: vmcnt retires oldest-first, so vmcnt(6) of 12 outstanding
// = stage(it+1) complete. WAR: STAGE((it+2)%3) overwrites buf(it-1), whose
// ds_reads retired before the iter-(it-1) barrier (MFMA lgkmcnt dependency).
__device__ __forceinline__ void gemm_tile_body(
    const unsigned short* __restrict__ A, const unsigned short* __restrict__ Bt,
    unsigned short* __restrict__ C, const float* __restrict__ bias,
    int has_bias_relu, int M, int tileM, int tileN,
    unsigned short* lsA, unsigned short* lsB) {
    const int t = threadIdx.x;
    const int lane = t & 63;
    const int wave = t >> 6;
    const int wm = wave >> 1, wn = wave & 1;
    const int quad = lane >> 4, r16 = lane & 15;

    floatx4 acc[4][2] = {};

    const unsigned short* ap[4];
#pragma unroll
    for (int q = 0; q < 4; ++q) {
        const int c = t + 256 * q;
        const int row = c >> 3;
        int g = tileM + row; if (g >= M) g = M - 1;
        ap[q] = A + (size_t)g * 512 + (((c & 7) ^ (row & 7)) * 8);
    }
    const unsigned short* bp[2];
#pragma unroll
    for (int q = 0; q < 2; ++q) {
        const int c = t + 256 * q;
        const int row = c >> 3;
        bp[q] = Bt + (size_t)(tileN + row) * 512 + (((c & 7) ^ (row & 7)) * 8);
    }

#define STAGE(buf, k0)                                                   \
    do {                                                                 \
        unsigned short* dA = lsA + (buf) * (128 * 64);                   \
        unsigned short* dB = lsB + (buf) * (64 * 64);                    \
        gl_lds16(ap[0] + (k0), dA + (size_t)t * 8);                      \
        gl_lds16(ap[1] + (k0), dA + (size_t)(t + 256) * 8);              \
        gl_lds16(ap[2] + (k0), dA + (size_t)(t + 512) * 8);              \
        gl_lds16(ap[3] + (k0), dA + (size_t)(t + 768) * 8);              \
        gl_lds16(bp[0] + (k0), dB + (size_t)t * 8);                      \
        gl_lds16(bp[1] + (k0), dB + (size_t)(t + 256) * 8);              \
    } while (0)

    STAGE(0, 0);
    STAGE(1, 64);
    asm volatile("s_waitcnt vmcnt(6)" ::: "memory");  // stage 0 done, stage 1 in flight
    __builtin_amdgcn_s_barrier();

#pragma unroll
    for (int it = 0; it < 8; ++it) {
        if (it < 6) STAGE((it + 2) % 3, (it + 2) * 64);  // 2-ahead prefetch
        const unsigned short* cA = lsA + (it % 3) * (128 * 64);
        const unsigned short* cB = lsB + (it % 3) * (64 * 64);

        short8 af[4][2], bfr[2][2];
#pragma unroll
        for (int i = 0; i < 4; ++i) {
            const int row = wm * 64 + i * 16 + r16;
#pragma unroll
            for (int kk = 0; kk < 2; ++kk) {
                const int kcw = kk * 4 + quad;
                af[i][kk] = *(const short8*)&cA[(size_t)(row * 8 + (kcw ^ (row & 7))) * 8];
            }
        }
#pragma unroll
        for (int j = 0; j < 2; ++j) {
            const int row = wn * 32 + j * 16 + r16;
#pragma unroll
            for (int kk = 0; kk < 2; ++kk) {
                const int kcw = kk * 4 + quad;
                bfr[j][kk] = *(const short8*)&cB[(size_t)(row * 8 + (kcw ^ (row & 7))) * 8];
            }
        }
#pragma unroll
        for (int kk = 0; kk < 2; ++kk)  // K ascending -> numerics match r3 exactly
#pragma unroll
            for (int i = 0; i < 4; ++i)
#pragma unroll
                for (int j = 0; j < 2; ++j)
                    acc[i][j] = __builtin_amdgcn_mfma_f32_16x16x32_bf16(af[i][kk], bfr[j][kk], acc[i][j], 0, 0, 0);

        // wait targets stage(it+1) (issued last iter); stage(it+2) stays in flight
        if (it < 6)       asm volatile("s_waitcnt vmcnt(6)" ::: "memory");
        else if (it == 6) asm volatile("s_waitcnt vmcnt(0)" ::: "memory");
        if (it < 7) __builtin_amdgcn_s_barrier();
    }
#undef STAGE

#pragma unroll
    for (int i = 0; i < 4; ++i) {
#pragma unroll
        for (int j = 0; j < 2; ++j) {
            const int col = tileN + wn * 32 + j * 16 + r16;
#pragma unroll
            for (int reg = 0; reg < 4; ++reg) {
                const int row = tileM + wm * 64 + i * 16 + quad * 4 + reg;
                if (row < M) {
                    float v = acc[i][j][reg];
                    if (has_bias_relu) { v += bias[col]; v = fmaxf(v, 0.f); }
                    C[(size_t)row * 512 + col] = f2bf(v);
                }
            }
        }
    }
}

// XCD-aware launch wrapper: grid = 640 linear blocks. Decode so that all 8
// N-slices of one M-tile share (L % 8) -> same XCD (round-robin dispatch
// heuristic) -> A-tile lands in that XCD's L2 once, reused 8x.
// LDS 72KB -> 2 blocks/CU; grid only supplies 2.5/CU so no occupancy loss.
__global__ __launch_bounds__(256)
void gemm_bf16_xcd(const unsigned short* __restrict__ A, const unsigned short* __restrict__ Bt,
                   unsigned short* __restrict__ C, const float* __restrict__ bias,
                   int has_bias_relu, int M) {
    __shared__ __align__(16) unsigned short lsA[3 * 128 * 64];  // 48 KB (3-ring)
    __shared__ __align__(16) unsigned short lsB[3 * 64 * 64];   // 24 KB
    const int L = blockIdx.x;
    const int m_low = L & 7;
    const int rest = L >> 3;         // 0..79
    const int n = rest & 7;          // 0..7
    const int m_high = rest >> 3;    // 0..9
    const int m = m_high * 8 + m_low;  // 0..79
    gemm_tile_body(A, Bt, C, bias, has_bias_relu, M, m * 128, n * 64, lsA, lsB);
}

// ---------- SpMM + bias + relu on padded CSR ----------
// r1: prefetch REVERTED (rows avg 2-3 rounds; it doubled uniform edge-loads
// for no latency win at 32 waves/CU TLP). readfirstlane on row bounds makes
// s,e provably wave-uniform -> cols/vals loads become scalar (s_load) paths.
// Packed bf16 unpack kept; per-element accumulation chains identical to r3.
__global__ __launch_bounds__(256)
void spmm_pad(const int* __restrict__ prow, const int* __restrict__ cols,
              const float* __restrict__ vals, const unsigned short* __restrict__ hmat,
              const float* __restrict__ bias, unsigned short* __restrict__ xout) {
    const int wave = threadIdx.x >> 6, lane = threadIdx.x & 63;
    const int r = blockIdx.x * 4 + wave;
    if (r >= NNODES) return;
    int s = prow[r], e = prow[r + 1];  // length is a multiple of 8
    s = __builtin_amdgcn_readfirstlane(s);  // wave-uniform by construction
    e = __builtin_amdgcn_readfirstlane(e);
    const int cb = lane * 8;
    floatx2 acc2[4] = {};

    for (int i = s; i < e; i += 8) {
        int c[8]; float v[8];
#pragma unroll
        for (int u = 0; u < 8; ++u) { c[u] = cols[i + u]; v[u] = vals[i + u]; }
        uint4 g[8];
#pragma unroll
        for (int u = 0; u < 8; ++u) g[u] = *(const uint4*)(hmat + (size_t)c[u] * H + cb);

#pragma unroll
        for (int u = 0; u < 8; ++u) {  // real-edge order preserved; pads are exact +0
            const floatx2 vv = {v[u], v[u]};
            union { unsigned int u_; float f; } lo, hi;
            floatx2 p;
            lo.u_ = g[u].x << 16; hi.u_ = g[u].x & 0xffff0000u;
            p[0] = lo.f; p[1] = hi.f; acc2[0] += vv * p;
            lo.u_ = g[u].y << 16; hi.u_ = g[u].y & 0xffff0000u;
            p[0] = lo.f; p[1] = hi.f; acc2[1] += vv * p;
            lo.u_ = g[u].z << 16; hi.u_ = g[u].z & 0xffff0000u;
            p[0] = lo.f; p[1] = hi.f; acc2[2] += vv * p;
            lo.u_ = g[u].w << 16; hi.u_ = g[u].w & 0xffff0000u;
            p[0] = lo.f; p[1] = hi.f; acc2[3] += vv * p;
        }
    }

    short8 o;
#pragma unroll
    for (int k = 0; k < 4; ++k) {
        o[2 * k]     = (short)f2bf(fmaxf(acc2[k][0] + bias[cb + 2 * k], 0.f));
        o[2 * k + 1] = (short)f2bf(fmaxf(acc2[k][1] + bias[cb + 2 * k + 1], 0.f));
    }
    *(short8*)(xout + (size_t)r * H + cb) = o;
}

// ---------- head: out[r] = sigmoid(dot(h2[r,:], w2) + b2) ----------
__global__ __launch_bounds__(256)
void final_head(const unsigned short* __restrict__ h2, const float* __restrict__ w2,
                const float* __restrict__ b2, float* __restrict__ out, int n) {
    const int wave = threadIdx.x >> 6, lane = threadIdx.x & 63;
    const int r = blockIdx.x * 4 + wave;
    if (r >= n) return;
    const unsigned short* hrow = h2 + (size_t)r * H;
    float acc = 0.f;
#pragma unroll
    for (int i = 0; i < 8; ++i) {
        const int c = lane * 8 + i;
        acc += bf2f(hrow[c]) * w2[c];
    }
#pragma unroll
    for (int off = 32; off >= 1; off >>= 1) acc += __shfl_xor(acc, off, 64);
    if (lane == 0) out[r] = 1.f / (1.f + expf(-(acc + b2[0])));
}

extern "C" void kernel_launch(void* const* d_in, const int* in_sizes, int n_in,
                              void* d_out, int out_size, void* d_ws, size_t ws_size,
                              hipStream_t stream) {
    (void)in_sizes; (void)n_in; (void)out_size; (void)ws_size;
    const float* feat   = (const float*)d_in[0];
    const int* adj_row  = (const int*)d_in[1];
    const int* adj_col  = (const int*)d_in[2];
    const float* adj_val= (const float*)d_in[3];
    const float* Wg     = (const float*)d_in[4];
    const float* bg     = (const float*)d_in[5];
    const float* vw1    = (const float*)d_in[6];
    const float* vb1    = (const float*)d_in[7];
    const float* vw2    = (const float*)d_in[8];
    const float* vb2    = (const float*)d_in[9];
    float* out = (float*)d_out;

    // workspace layout (bytes)
    char* ws = (char*)d_ws;
    unsigned short* x  = (unsigned short*)(ws + 0);          // 10,240,000
    unsigned short* h  = (unsigned short*)(ws + 10240000);   // 10,240,000
    unsigned short* Wt = (unsigned short*)(ws + 20480000);   // 3,145,728
    int*   prow    = (int*)(ws + 23625728);                  // 160,064
    int*   counts  = (int*)(ws + 23785792);                  // 40,000
    int*   fill    = (int*)(ws + 23825792);                  // 40,000 (contiguous after counts)
    int*   colsP   = (int*)(ws + 23865792);                  // 960,000 (240k padded edges)
    float* valsP   = (float*)(ws + 24825792);                // 960,000 -> ~25.8 MB

    // --- prep ---
    zero_int<<<(20000 + 255) / 256, 256, 0, stream>>>(counts, 20000);          // counts + fill
    zero_int<<<(480000 + 255) / 256, 256, 0, stream>>>(colsP, 480000);         // colsP + valsP (pad slots)
    cvt_f32_bf16<<<(NNODES * H / 4 + 255) / 256, 256, 0, stream>>>(feat, x, NNODES * H / 4);
    transpose_cvt6<<<dim3(16, 16, 6), dim3(32, 8), 0, stream>>>(Wg, vw1, Wt);
    edge_hist<<<(NEDGES + 255) / 256, 256, 0, stream>>>(adj_row, counts, NEDGES);
    scan_rows_pad<<<1, 1024, 0, stream>>>(counts, prow, NNODES);
    edge_scatter<<<(NEDGES + 255) / 256, 256, 0, stream>>>(adj_row, adj_col, adj_val,
                                                           prow, fill, colsP, valsP, NEDGES);

    // --- layers ---
    for (int l = 0; l < NLAYERS; ++l) {
        gemm_bf16_xcd<<<640, 256, 0, stream>>>(x, Wt + (size_t)l * H * H, h, nullptr, 0, NNODES);
        spmm_pad<<<(NNODES + 3) / 4, 256, 0, stream>>>(prow, colsP, valsP, h, bg + (size_t)l * H, x);
    }
    gemm_bf16_xcd<<<640, 256, 0, stream>>>(x, Wt + (size_t)NLAYERS * H * H, h, vb1, 1, NNODES);
    final_head<<<(NNODES + 3) / 4, 256, 0, stream>>>(h, vw2, vb2, out, NNODES);
}

// Round 3
// 318.140 us; speedup vs baseline: 1.0888x; 1.0888x over previous
//
#include <hip/hip_runtime.h>

#define H 512
#define NNODES 10000
#define NEDGES 160000
#define NLAYERS 5

typedef __attribute__((ext_vector_type(8))) short short8;
typedef __attribute__((ext_vector_type(4))) float floatx4;

// ---------- helpers ----------
__device__ inline unsigned short f2bf(float v) {
    union { float f; unsigned int u; } x; x.f = v;
    unsigned int r = (x.u + 0x7fffu + ((x.u >> 16) & 1u)) >> 16;
    return (unsigned short)r;
}
__device__ inline float bf2f(unsigned short u) {
    union { unsigned int u; float f; } x; x.u = ((unsigned int)u) << 16; return x.f;
}
__device__ inline void gl_lds16(const void* g, void* l) {
    __builtin_amdgcn_global_load_lds((const __attribute__((address_space(1))) void*)g,
                                     (__attribute__((address_space(3))) void*)l, 16, 0, 0);
}

// ---------- fused prep: zero(500k ints) + cvt feat->bf16 + transpose 6 weights ----------
// The three jobs are mutually independent -> one dispatch (was 4 dispatches).
// Block ranges: [0,1954) zero, [1954,6954) cvt, [6954,8490) transpose.
#define ZB 1954
#define CB 5000
#define TB 1536  // 16*16*6

__global__ __launch_bounds__(256)
void prep_fused(int* __restrict__ zero_base, const float* __restrict__ feat,
                unsigned short* __restrict__ x, const float* __restrict__ Wg,
                const float* __restrict__ vw1, unsigned short* __restrict__ Wt) {
    __shared__ float tile[32][33];
    const int b = blockIdx.x;
    const int t = threadIdx.x;
    if (b < ZB) {
        int i = b * 256 + t;
        if (i < 500000) zero_base[i] = 0;   // counts+fill+colsP+valsP (contiguous)
    } else if (b < ZB + CB) {
        int i = (b - ZB) * 256 + t;         // exactly 1,280,000 float4 groups
        float4 v = ((const float4*)feat)[i];
        ushort4 o;
        o.x = f2bf(v.x); o.y = f2bf(v.y); o.z = f2bf(v.z); o.w = f2bf(v.w);
        ((ushort4*)x)[i] = o;
    } else {
        const int bb = b - ZB - CB;         // 0..1535
        const int z = bb >> 8;              // 0..5
        const int rem = bb & 255;
        const int by = (rem >> 4) * 32;
        const int bx = (rem & 15) * 32;
        const float* in = (z < NLAYERS) ? (Wg + (size_t)z * H * H) : vw1;
        unsigned short* out = Wt + (size_t)z * H * H;
        const int tx = t & 31, ty = t >> 5; // (32,8)
        for (int i = ty; i < 32; i += 8)
            tile[i][tx] = in[(size_t)(by + i) * H + bx + tx];
        __syncthreads();
        for (int i = ty; i < 32; i += 8)
            out[(size_t)(bx + i) * H + by + tx] = f2bf(tile[tx][i]);
    }
}

__global__ void edge_hist(const int* __restrict__ rows, int* __restrict__ counts, int n) {
    int i = blockIdx.x * blockDim.x + threadIdx.x;
    if (i < n) atomicAdd(&counts[rows[i]], 1);
}

// prefix-sum of row counts PADDED to multiples of 8 (dummy edges have val=0
// -> exact no-ops in the accumulation; enables branch-free SpMM rounds)
__global__ __launch_bounds__(1024)
void scan_rows_pad(const int* __restrict__ counts, int* __restrict__ row_ptr, int n) {
    __shared__ int sums[1024];
    const int t = threadIdx.x;
    const int base = t * 16;
    int local[16];
    int s = 0;
#pragma unroll
    for (int i = 0; i < 16; ++i) {
        int idx = base + i;
        int v = (idx < n) ? ((counts[idx] + 7) & ~7) : 0;
        local[i] = s;
        s += v;
    }
    sums[t] = s;
    __syncthreads();
    for (int off = 1; off < 1024; off <<= 1) {
        int v = (t >= off) ? sums[t - off] : 0;
        __syncthreads();
        sums[t] += v;
        __syncthreads();
    }
    const int prefix = (t == 0) ? 0 : sums[t - 1];
#pragma unroll
    for (int i = 0; i < 16; ++i) {
        int idx = base + i;
        if (idx < n) row_ptr[idx] = prefix + local[i];
    }
    if (t == 0) row_ptr[n] = sums[1023];
}

__global__ void edge_scatter(const int* __restrict__ rows, const int* __restrict__ colsin,
                             const float* __restrict__ valsin, const int* __restrict__ row_ptr,
                             int* __restrict__ fill, int* __restrict__ colsout,
                             float* __restrict__ valsout, int n) {
    int i = blockIdx.x * blockDim.x + threadIdx.x;
    if (i < n) {
        int r = rows[i];
        int pos = row_ptr[r] + atomicAdd(&fill[r], 1);
        colsout[pos] = colsin[i];
        valsout[pos] = valsin[i];
    }
}

// ---------- GEMM (r2: 64x64 tile, BK=64, XOR k-slot swizzle, single-buffer) ----------
// Reverted to the PROVEN r3 sync structure (stage -> barrier -> compute ->
// barrier; no hand vmcnt, no multi-buffer -- r0/r1 showed those regress).
// Geometry change only: 128x64 -> 64x64 doubles the grid (640 -> 1280 =
// 5 blocks/CU resident vs 2.5) so cross-block overlap hides the stage
// latency that the single-buffer loop exposes. Swizzle, fragment layout and
// K-accumulation order are unchanged -> bit-identical numerics vs baseline.
__global__ __launch_bounds__(256)
void gemm_bf16_xcd(const unsigned short* __restrict__ A, const unsigned short* __restrict__ Bt,
                   unsigned short* __restrict__ C, const float* __restrict__ bias,
                   int has_bias_relu, int M) {
    __shared__ __align__(16) unsigned short lsA[64 * 64];  // 8 KB
    __shared__ __align__(16) unsigned short lsB[64 * 64];  // 8 KB
    // XCD decode: all 8 N-slices of one M-tile share (L % 8) -> same XCD ->
    // A-tile fetched into that XCD's L2 once, reused 8x.
    const int L = blockIdx.x;
    const int m_low = L & 7;
    const int rest = L >> 3;          // 0..159
    const int n = rest & 7;           // 0..7
    const int m_high = rest >> 3;     // 0..19
    const int m = m_high * 8 + m_low; // 0..159
    const int tileM = m * 64, tileN = n * 64;

    const int t = threadIdx.x;
    const int lane = t & 63;
    const int wave = t >> 6;
    const int wm = wave >> 1, wn = wave & 1;
    const int quad = lane >> 4, r16 = lane & 15;

    floatx4 acc[2][2] = {};

    const unsigned short* ap[2];
#pragma unroll
    for (int q = 0; q < 2; ++q) {
        const int c = t + 256 * q;      // 0..511
        const int row = c >> 3;         // 0..63
        int g = tileM + row; if (g >= M) g = M - 1;
        ap[q] = A + (size_t)g * 512 + (((c & 7) ^ (row & 7)) * 8);
    }
    const unsigned short* bp[2];
#pragma unroll
    for (int q = 0; q < 2; ++q) {
        const int c = t + 256 * q;
        const int row = c >> 3;
        bp[q] = Bt + (size_t)(tileN + row) * 512 + (((c & 7) ^ (row & 7)) * 8);
    }

    for (int k0 = 0; k0 < 512; k0 += 64) {
        gl_lds16(ap[0] + k0, lsA + (size_t)t * 8);
        gl_lds16(ap[1] + k0, lsA + (size_t)(t + 256) * 8);
        gl_lds16(bp[0] + k0, lsB + (size_t)t * 8);
        gl_lds16(bp[1] + k0, lsB + (size_t)(t + 256) * 8);
        __syncthreads();

        short8 af[2][2], bfr[2][2];
#pragma unroll
        for (int i = 0; i < 2; ++i) {
            const int row = wm * 32 + i * 16 + r16;
#pragma unroll
            for (int kk = 0; kk < 2; ++kk) {
                const int kcw = kk * 4 + quad;
                af[i][kk] = *(const short8*)&lsA[(size_t)(row * 8 + (kcw ^ (row & 7))) * 8];
            }
        }
#pragma unroll
        for (int j = 0; j < 2; ++j) {
            const int row = wn * 32 + j * 16 + r16;
#pragma unroll
            for (int kk = 0; kk < 2; ++kk) {
                const int kcw = kk * 4 + quad;
                bfr[j][kk] = *(const short8*)&lsB[(size_t)(row * 8 + (kcw ^ (row & 7))) * 8];
            }
        }
#pragma unroll
        for (int kk = 0; kk < 2; ++kk)  // K ascending -> numerics identical to baseline
#pragma unroll
            for (int i = 0; i < 2; ++i)
#pragma unroll
                for (int j = 0; j < 2; ++j)
                    acc[i][j] = __builtin_amdgcn_mfma_f32_16x16x32_bf16(af[i][kk], bfr[j][kk], acc[i][j], 0, 0, 0);
        __syncthreads();
    }

#pragma unroll
    for (int i = 0; i < 2; ++i) {
#pragma unroll
        for (int j = 0; j < 2; ++j) {
            const int col = tileN + wn * 32 + j * 16 + r16;
#pragma unroll
            for (int reg = 0; reg < 4; ++reg) {
                const int row = tileM + wm * 32 + i * 16 + quad * 4 + reg;
                if (row < M) {
                    float v = acc[i][j][reg];
                    if (has_bias_relu) { v += bias[col]; v = fmaxf(v, 0.f); }
                    C[(size_t)row * 512 + col] = f2bf(v);
                }
            }
        }
    }
}

// ---------- SpMM + bias + relu on padded CSR: branch-free unroll-8 rounds ----------
// Exact revert to the proven 325us baseline version.
__global__ __launch_bounds__(256)
void spmm_pad(const int* __restrict__ prow, const int* __restrict__ cols,
              const float* __restrict__ vals, const unsigned short* __restrict__ hmat,
              const float* __restrict__ bias, unsigned short* __restrict__ xout) {
    const int wave = threadIdx.x >> 6, lane = threadIdx.x & 63;
    const int r = blockIdx.x * 4 + wave;
    if (r >= NNODES) return;
    const int s = prow[r], e = prow[r + 1];  // length is a multiple of 8
    const int cb = lane * 8;
    float acc[8] = {0.f, 0.f, 0.f, 0.f, 0.f, 0.f, 0.f, 0.f};

    for (int i = s; i < e; i += 8) {
        int c[8]; float v[8]; short8 g[8];
#pragma unroll
        for (int u = 0; u < 8; ++u) { c[u] = cols[i + u]; v[u] = vals[i + u]; }
#pragma unroll
        for (int u = 0; u < 8; ++u) g[u] = *(const short8*)(hmat + (size_t)c[u] * H + cb);
#pragma unroll
        for (int u = 0; u < 8; ++u)  // real-edge order preserved; pads are exact +0
#pragma unroll
            for (int j = 0; j < 8; ++j) acc[j] += v[u] * bf2f((unsigned short)g[u][j]);
    }

    short8 o;
#pragma unroll
    for (int j = 0; j < 8; ++j)
        o[j] = (short)f2bf(fmaxf(acc[j] + bias[cb + j], 0.f));
    *(short8*)(xout + (size_t)r * H + cb) = o;
}

// ---------- head: out[r] = sigmoid(dot(h2[r,:], w2) + b2) ----------
__global__ __launch_bounds__(256)
void final_head(const unsigned short* __restrict__ h2, const float* __restrict__ w2,
                const float* __restrict__ b2, float* __restrict__ out, int n) {
    const int wave = threadIdx.x >> 6, lane = threadIdx.x & 63;
    const int r = blockIdx.x * 4 + wave;
    if (r >= n) return;
    const unsigned short* hrow = h2 + (size_t)r * H;
    float acc = 0.f;
#pragma unroll
    for (int i = 0; i < 8; ++i) {
        const int c = lane * 8 + i;
        acc += bf2f(hrow[c]) * w2[c];
    }
#pragma unroll
    for (int off = 32; off >= 1; off >>= 1) acc += __shfl_xor(acc, off, 64);
    if (lane == 0) out[r] = 1.f / (1.f + expf(-(acc + b2[0])));
}

extern "C" void kernel_launch(void* const* d_in, const int* in_sizes, int n_in,
                              void* d_out, int out_size, void* d_ws, size_t ws_size,
                              hipStream_t stream) {
    (void)in_sizes; (void)n_in; (void)out_size; (void)ws_size;
    const float* feat   = (const float*)d_in[0];
    const int* adj_row  = (const int*)d_in[1];
    const int* adj_col  = (const int*)d_in[2];
    const float* adj_val= (const float*)d_in[3];
    const float* Wg     = (const float*)d_in[4];
    const float* bg     = (const float*)d_in[5];
    const float* vw1    = (const float*)d_in[6];
    const float* vb1    = (const float*)d_in[7];
    const float* vw2    = (const float*)d_in[8];
    const float* vb2    = (const float*)d_in[9];
    float* out = (float*)d_out;

    // workspace layout (bytes)
    char* ws = (char*)d_ws;
    unsigned short* x  = (unsigned short*)(ws + 0);          // 10,240,000
    unsigned short* h  = (unsigned short*)(ws + 10240000);   // 10,240,000
    unsigned short* Wt = (unsigned short*)(ws + 20480000);   // 3,145,728
    int*   prow    = (int*)(ws + 23625728);                  // 160,064
    int*   counts  = (int*)(ws + 23785792);                  // 40,000
    int*   fill    = (int*)(ws + 23825792);                  // 40,000 (contiguous after counts)
    int*   colsP   = (int*)(ws + 23865792);                  // 960,000 (240k padded edges)
    float* valsP   = (float*)(ws + 24825792);                // 960,000 -> ~25.8 MB
    // counts..valsP-end is one contiguous 2,000,000-byte region -> single zero.

    // --- prep (4 dispatches, was 7) ---
    prep_fused<<<ZB + CB + TB, 256, 0, stream>>>(counts, feat, x, Wg, vw1, Wt);
    edge_hist<<<(NEDGES + 255) / 256, 256, 0, stream>>>(adj_row, counts, NEDGES);
    scan_rows_pad<<<1, 1024, 0, stream>>>(counts, prow, NNODES);
    edge_scatter<<<(NEDGES + 255) / 256, 256, 0, stream>>>(adj_row, adj_col, adj_val,
                                                           prow, fill, colsP, valsP, NEDGES);

    // --- layers ---
    for (int l = 0; l < NLAYERS; ++l) {
        gemm_bf16_xcd<<<1280, 256, 0, stream>>>(x, Wt + (size_t)l * H * H, h, nullptr, 0, NNODES);
        spmm_pad<<<(NNODES + 3) / 4, 256, 0, stream>>>(prow, colsP, valsP, h, bg + (size_t)l * H, x);
    }
    gemm_bf16_xcd<<<1280, 256, 0, stream>>>(x, Wt + (size_t)NLAYERS * H * H, h, vb1, 1, NNODES);
    final_head<<<(NNODES + 3) / 4, 256, 0, stream>>>(h, vw2, vb2, out, NNODES);
}

// Round 4
// 307.790 us; speedup vs baseline: 1.1254x; 1.0336x over previous
//
#include <hip/hip_runtime.h>

#define H 512
#define NNODES 10000
#define NEDGES 160000
#define NLAYERS 5
#define CAP 64   // fixed per-row edge capacity; max degree of Binomial(160k,1e-4) over 10k rows ~ 33

typedef __attribute__((ext_vector_type(8))) short short8;
typedef __attribute__((ext_vector_type(4))) float floatx4;

// ---------- helpers ----------
__device__ inline unsigned short f2bf(float v) {
    union { float f; unsigned int u; } x; x.f = v;
    unsigned int r = (x.u + 0x7fffu + ((x.u >> 16) & 1u)) >> 16;
    return (unsigned short)r;
}
__device__ inline float bf2f(unsigned short u) {
    union { unsigned int u; float f; } x; x.u = ((unsigned int)u) << 16; return x.f;
}
__device__ inline void gl_lds16(const void* g, void* l) {
    __builtin_amdgcn_global_load_lds((const __attribute__((address_space(1))) void*)g,
                                     (__attribute__((address_space(3))) void*)l, 16, 0, 0);
}

// ---------- fused prep: zero(1.29M ints) + cvt feat->bf16 + transpose 6 weights ----------
// Block ranges: [0,ZB) zero fill+colsP+valsP (contiguous 5.16MB),
// [ZB,ZB+CB) cvt, [ZB+CB,ZB+CB+TB) transpose.
#define ZB 5040   // ceil(1,290,000 / 256)
#define CB 5000   // 1,280,000 float4 groups / 256
#define TB 1536   // 16*16*6

__global__ __launch_bounds__(256)
void prep_fused(int* __restrict__ zero_base, const float* __restrict__ feat,
                unsigned short* __restrict__ x, const float* __restrict__ Wg,
                const float* __restrict__ vw1, unsigned short* __restrict__ Wt) {
    __shared__ float tile[32][33];
    const int b = blockIdx.x;
    const int t = threadIdx.x;
    if (b < ZB) {
        int i = b * 256 + t;
        if (i < 1290000) zero_base[i] = 0;  // fill + colsP + valsP (contiguous)
    } else if (b < ZB + CB) {
        int i = (b - ZB) * 256 + t;         // exactly 1,280,000 float4 groups
        float4 v = ((const float4*)feat)[i];
        ushort4 o;
        o.x = f2bf(v.x); o.y = f2bf(v.y); o.z = f2bf(v.z); o.w = f2bf(v.w);
        ((ushort4*)x)[i] = o;
    } else {
        const int bb = b - ZB - CB;         // 0..1535
        const int z = bb >> 8;              // 0..5
        const int rem = bb & 255;
        const int by = (rem >> 4) * 32;
        const int bx = (rem & 15) * 32;
        const float* in = (z < NLAYERS) ? (Wg + (size_t)z * H * H) : vw1;
        unsigned short* out = Wt + (size_t)z * H * H;
        const int tx = t & 31, ty = t >> 5; // (32,8)
        for (int i = ty; i < 32; i += 8)
            tile[i][tx] = in[(size_t)(by + i) * H + bx + tx];
        __syncthreads();
        for (int i = ty; i < 32; i += 8)
            out[(size_t)(bx + i) * H + by + tx] = f2bf(tile[tx][i]);
    }
}

// ---------- direct scatter into fixed-capacity padded rows ----------
// Replaces hist + single-block scan + scatter (3 dispatches, one of which
// idled 255/256 CUs). Dummy slots stay zeroed: val=0 -> exact +0 in SpMM,
// col=0 -> gathers the L2-hot row 0. pos guard is memory-safety only
// (deg>CAP has probability ~1e-20 under the fixed input distribution).
__global__ void edge_scatter_direct(const int* __restrict__ rows, const int* __restrict__ colsin,
                                    const float* __restrict__ valsin, int* __restrict__ fill,
                                    int* __restrict__ colsout, float* __restrict__ valsout, int n) {
    int i = blockIdx.x * blockDim.x + threadIdx.x;
    if (i < n) {
        int r = rows[i];
        int pos = atomicAdd(&fill[r], 1);
        if (pos < CAP) {
            colsout[r * CAP + pos] = colsin[i];
            valsout[r * CAP + pos] = valsin[i];
        }
    }
}

// ---------- GEMM (64x64 tile, BK=64, XOR k-slot swizzle, single-buffer) ----------
// PROVEN r2 structure -- do not touch the sync structure (r0/r1 lessons).
__global__ __launch_bounds__(256)
void gemm_bf16_xcd(const unsigned short* __restrict__ A, const unsigned short* __restrict__ Bt,
                   unsigned short* __restrict__ C, const float* __restrict__ bias,
                   int has_bias_relu, int M) {
    __shared__ __align__(16) unsigned short lsA[64 * 64];  // 8 KB
    __shared__ __align__(16) unsigned short lsB[64 * 64];  // 8 KB
    // XCD decode: all 8 N-slices of one M-tile share (L % 8) -> same XCD ->
    // A-tile fetched into that XCD's L2 once, reused 8x.
    const int L = blockIdx.x;
    const int m_low = L & 7;
    const int rest = L >> 3;          // 0..159
    const int n = rest & 7;           // 0..7
    const int m_high = rest >> 3;     // 0..19
    const int m = m_high * 8 + m_low; // 0..159
    const int tileM = m * 64, tileN = n * 64;

    const int t = threadIdx.x;
    const int lane = t & 63;
    const int wave = t >> 6;
    const int wm = wave >> 1, wn = wave & 1;
    const int quad = lane >> 4, r16 = lane & 15;

    floatx4 acc[2][2] = {};

    const unsigned short* ap[2];
#pragma unroll
    for (int q = 0; q < 2; ++q) {
        const int c = t + 256 * q;      // 0..511
        const int row = c >> 3;         // 0..63
        int g = tileM + row; if (g >= M) g = M - 1;
        ap[q] = A + (size_t)g * 512 + (((c & 7) ^ (row & 7)) * 8);
    }
    const unsigned short* bp[2];
#pragma unroll
    for (int q = 0; q < 2; ++q) {
        const int c = t + 256 * q;
        const int row = c >> 3;
        bp[q] = Bt + (size_t)(tileN + row) * 512 + (((c & 7) ^ (row & 7)) * 8);
    }

    for (int k0 = 0; k0 < 512; k0 += 64) {
        gl_lds16(ap[0] + k0, lsA + (size_t)t * 8);
        gl_lds16(ap[1] + k0, lsA + (size_t)(t + 256) * 8);
        gl_lds16(bp[0] + k0, lsB + (size_t)t * 8);
        gl_lds16(bp[1] + k0, lsB + (size_t)(t + 256) * 8);
        __syncthreads();

        short8 af[2][2], bfr[2][2];
#pragma unroll
        for (int i = 0; i < 2; ++i) {
            const int row = wm * 32 + i * 16 + r16;
#pragma unroll
            for (int kk = 0; kk < 2; ++kk) {
                const int kcw = kk * 4 + quad;
                af[i][kk] = *(const short8*)&lsA[(size_t)(row * 8 + (kcw ^ (row & 7))) * 8];
            }
        }
#pragma unroll
        for (int j = 0; j < 2; ++j) {
            const int row = wn * 32 + j * 16 + r16;
#pragma unroll
            for (int kk = 0; kk < 2; ++kk) {
                const int kcw = kk * 4 + quad;
                bfr[j][kk] = *(const short8*)&lsB[(size_t)(row * 8 + (kcw ^ (row & 7))) * 8];
            }
        }
#pragma unroll
        for (int kk = 0; kk < 2; ++kk)  // K ascending -> numerics identical to baseline
#pragma unroll
            for (int i = 0; i < 2; ++i)
#pragma unroll
                for (int j = 0; j < 2; ++j)
                    acc[i][j] = __builtin_amdgcn_mfma_f32_16x16x32_bf16(af[i][kk], bfr[j][kk], acc[i][j], 0, 0, 0);
        __syncthreads();
    }

#pragma unroll
    for (int i = 0; i < 2; ++i) {
#pragma unroll
        for (int j = 0; j < 2; ++j) {
            const int col = tileN + wn * 32 + j * 16 + r16;
#pragma unroll
            for (int reg = 0; reg < 4; ++reg) {
                const int row = tileM + wm * 32 + i * 16 + quad * 4 + reg;
                if (row < M) {
                    float v = acc[i][j][reg];
                    if (has_bias_relu) { v += bias[col]; v = fmaxf(v, 0.f); }
                    C[(size_t)row * 512 + col] = f2bf(v);
                }
            }
        }
    }
}

// ---------- SpMM + bias + relu on fixed-capacity padded rows ----------
// Same proven inner loop as the 318us baseline; only the source of (s,e)
// changed: s = r*CAP, len = fill[r] rounded up to 8. readfirstlane makes the
// count wave-uniform so cols/vals index scalarizes (s_load path) -- pure
// load scalarization, accumulation order untouched.
__global__ __launch_bounds__(256)
void spmm_pad(const int* __restrict__ fill, const int* __restrict__ cols,
              const float* __restrict__ vals, const unsigned short* __restrict__ hmat,
              const float* __restrict__ bias, unsigned short* __restrict__ xout) {
    const int wave = threadIdx.x >> 6, lane = threadIdx.x & 63;
    const int r = blockIdx.x * 4 + wave;
    if (r >= NNODES) return;
    int cnt = fill[r];
    cnt = __builtin_amdgcn_readfirstlane(cnt);   // wave-uniform by construction
    const int s = r * CAP;
    const int e = s + ((cnt + 7) & ~7);
    const int cb = lane * 8;
    float acc[8] = {0.f, 0.f, 0.f, 0.f, 0.f, 0.f, 0.f, 0.f};

    for (int i = s; i < e; i += 8) {
        int c[8]; float v[8]; short8 g[8];
#pragma unroll
        for (int u = 0; u < 8; ++u) { c[u] = cols[i + u]; v[u] = vals[i + u]; }
#pragma unroll
        for (int u = 0; u < 8; ++u) g[u] = *(const short8*)(hmat + (size_t)c[u] * H + cb);
#pragma unroll
        for (int u = 0; u < 8; ++u)  // real-edge order preserved; pads are exact +0
#pragma unroll
            for (int j = 0; j < 8; ++j) acc[j] += v[u] * bf2f((unsigned short)g[u][j]);
    }

    short8 o;
#pragma unroll
    for (int j = 0; j < 8; ++j)
        o[j] = (short)f2bf(fmaxf(acc[j] + bias[cb + j], 0.f));
    *(short8*)(xout + (size_t)r * H + cb) = o;
}

// ---------- head: out[r] = sigmoid(dot(h2[r,:], w2) + b2) ----------
__global__ __launch_bounds__(256)
void final_head(const unsigned short* __restrict__ h2, const float* __restrict__ w2,
                const float* __restrict__ b2, float* __restrict__ out, int n) {
    const int wave = threadIdx.x >> 6, lane = threadIdx.x & 63;
    const int r = blockIdx.x * 4 + wave;
    if (r >= n) return;
    const unsigned short* hrow = h2 + (size_t)r * H;
    float acc = 0.f;
#pragma unroll
    for (int i = 0; i < 8; ++i) {
        const int c = lane * 8 + i;
        acc += bf2f(hrow[c]) * w2[c];
    }
#pragma unroll
    for (int off = 32; off >= 1; off >>= 1) acc += __shfl_xor(acc, off, 64);
    if (lane == 0) out[r] = 1.f / (1.f + expf(-(acc + b2[0])));
}

extern "C" void kernel_launch(void* const* d_in, const int* in_sizes, int n_in,
                              void* d_out, int out_size, void* d_ws, size_t ws_size,
                              hipStream_t stream) {
    (void)in_sizes; (void)n_in; (void)out_size; (void)ws_size;
    const float* feat   = (const float*)d_in[0];
    const int* adj_row  = (const int*)d_in[1];
    const int* adj_col  = (const int*)d_in[2];
    const float* adj_val= (const float*)d_in[3];
    const float* Wg     = (const float*)d_in[4];
    const float* bg     = (const float*)d_in[5];
    const float* vw1    = (const float*)d_in[6];
    const float* vb1    = (const float*)d_in[7];
    const float* vw2    = (const float*)d_in[8];
    const float* vb2    = (const float*)d_in[9];
    float* out = (float*)d_out;

    // workspace layout (bytes)
    char* ws = (char*)d_ws;
    unsigned short* x  = (unsigned short*)(ws + 0);          // 10,240,000
    unsigned short* h  = (unsigned short*)(ws + 10240000);   // 10,240,000
    unsigned short* Wt = (unsigned short*)(ws + 20480000);   // 3,145,728
    int*   fill    = (int*)(ws + 23625728);                  // 40,000
    int*   colsP   = (int*)(ws + 23665728);                  // 2,560,000 (CAP*NNODES ints)
    float* valsP   = (float*)(ws + 26225728);                // 2,560,000 -> ~28.8 MB total
    // fill..valsP-end is one contiguous 5,160,000-byte region -> single zero pass.

    // --- prep (2 dispatches; hist+scan+scatter chain replaced by direct scatter) ---
    prep_fused<<<ZB + CB + TB, 256, 0, stream>>>(fill, feat, x, Wg, vw1, Wt);
    edge_scatter_direct<<<(NEDGES + 255) / 256, 256, 0, stream>>>(adj_row, adj_col, adj_val,
                                                                  fill, colsP, valsP, NEDGES);

    // --- layers ---
    for (int l = 0; l < NLAYERS; ++l) {
        gemm_bf16_xcd<<<1280, 256, 0, stream>>>(x, Wt + (size_t)l * H * H, h, nullptr, 0, NNODES);
        spmm_pad<<<(NNODES + 3) / 4, 256, 0, stream>>>(fill, colsP, valsP, h, bg + (size_t)l * H, x);
    }
    gemm_bf16_xcd<<<1280, 256, 0, stream>>>(x, Wt + (size_t)NLAYERS * H * H, h, vb1, 1, NNODES);
    final_head<<<(NNODES + 3) / 4, 256, 0, stream>>>(h, vw2, vb2, out, NNODES);
}

// Round 5
// 288.676 us; speedup vs baseline: 1.1999x; 1.0662x over previous
//
#include <hip/hip_runtime.h>

#define H 512
#define NNODES 10000
#define NEDGES 160000
#define NLAYERS 5
#define CAP 64   // fixed per-row edge capacity; max degree of Binomial(160k,1e-4) over 10k rows ~ 33

typedef __attribute__((ext_vector_type(8))) short short8;
typedef __attribute__((ext_vector_type(4))) float floatx4;

// ---------- helpers ----------
__device__ inline unsigned short f2bf(float v) {
    union { float f; unsigned int u; } x; x.f = v;
    unsigned int r = (x.u + 0x7fffu + ((x.u >> 16) & 1u)) >> 16;
    return (unsigned short)r;
}
__device__ inline float bf2f(unsigned short u) {
    union { unsigned int u; float f; } x; x.u = ((unsigned int)u) << 16; return x.f;
}
__device__ inline void gl_lds16(const void* g, void* l) {
    __builtin_amdgcn_global_load_lds((const __attribute__((address_space(1))) void*)g,
                                     (__attribute__((address_space(3))) void*)l, 16, 0, 0);
}

// ---------- fused prep: zero(1.29M ints) + zero(out) + cvt feat->bf16 + transpose 6 weights ----------
// Block ranges: [0,ZB) zero fill+colsP+valsP, [ZB,ZB+CB) cvt,
// [ZB+CB,ZB+CB+TB) transpose, [ZB+CB+TB, +OB) zero out (head accumulator).
#define ZB 5040   // ceil(1,290,000 / 256)
#define CB 5000   // 1,280,000 float4 groups / 256
#define TB 1536   // 16*16*6
#define OB 40     // ceil(10,000 / 256)

__global__ __launch_bounds__(256)
void prep_fused(int* __restrict__ zero_base, const float* __restrict__ feat,
                unsigned short* __restrict__ x, const float* __restrict__ Wg,
                const float* __restrict__ vw1, unsigned short* __restrict__ Wt,
                float* __restrict__ outz) {
    __shared__ float tile[32][33];
    const int b = blockIdx.x;
    const int t = threadIdx.x;
    if (b < ZB) {
        int i = b * 256 + t;
        if (i < 1290000) zero_base[i] = 0;  // fill + colsP + valsP (contiguous)
    } else if (b < ZB + CB) {
        int i = (b - ZB) * 256 + t;         // exactly 1,280,000 float4 groups
        float4 v = ((const float4*)feat)[i];
        ushort4 o;
        o.x = f2bf(v.x); o.y = f2bf(v.y); o.z = f2bf(v.z); o.w = f2bf(v.w);
        ((ushort4*)x)[i] = o;
    } else if (b < ZB + CB + TB) {
        const int bb = b - ZB - CB;         // 0..1535
        const int z = bb >> 8;              // 0..5
        const int rem = bb & 255;
        const int by = (rem >> 4) * 32;
        const int bx = (rem & 15) * 32;
        const float* in = (z < NLAYERS) ? (Wg + (size_t)z * H * H) : vw1;
        unsigned short* out = Wt + (size_t)z * H * H;
        const int tx = t & 31, ty = t >> 5; // (32,8)
        for (int i = ty; i < 32; i += 8)
            tile[i][tx] = in[(size_t)(by + i) * H + bx + tx];
        __syncthreads();
        for (int i = ty; i < 32; i += 8)
            out[(size_t)(bx + i) * H + by + tx] = f2bf(tile[tx][i]);
    } else {
        int i = (b - ZB - CB - TB) * 256 + t;
        if (i < NNODES) outz[i] = 0.f;      // head partial-sum accumulator
    }
}

// ---------- direct scatter into fixed-capacity padded rows ----------
// Dummy slots stay zeroed: val=0 -> exact +0 in SpMM, col=0 -> gathers the
// L2-hot row 0. pos guard is memory-safety only (deg>CAP ~ impossible).
__global__ void edge_scatter_direct(const int* __restrict__ rows, const int* __restrict__ colsin,
                                    const float* __restrict__ valsin, int* __restrict__ fill,
                                    int* __restrict__ colsout, float* __restrict__ valsout, int n) {
    int i = blockIdx.x * blockDim.x + threadIdx.x;
    if (i < n) {
        int r = rows[i];
        int pos = atomicAdd(&fill[r], 1);
        if (pos < CAP) {
            colsout[r * CAP + pos] = colsin[i];
            valsout[r * CAP + pos] = valsin[i];
        }
    }
}

// ---------- GEMM (64x64 tile, BK=64, XOR k-slot swizzle, single-buffer) ----------
// PROVEN r2/r3 main-loop structure -- sync structure untouched (r0/r1 lessons).
// mode 0: plain bf16 store of C.
// mode 2: head fusion -- v = relu(acc + bias[col]); partial-dot with w2;
//         xor-tree reduce over the 16 r16-lanes (32-col partials); one
//         atomicAdd per (row, wave, N-block) into outp. No C store at all:
//         saves the 10MB h2 write + the 10MB final_head re-read.
__global__ __launch_bounds__(256)
void gemm_bf16_xcd(const unsigned short* __restrict__ A, const unsigned short* __restrict__ Bt,
                   unsigned short* __restrict__ C, const float* __restrict__ bias,
                   const float* __restrict__ w2, float* __restrict__ outp,
                   int mode, int M) {
    __shared__ __align__(16) unsigned short lsA[64 * 64];  // 8 KB
    __shared__ __align__(16) unsigned short lsB[64 * 64];  // 8 KB
    // XCD decode: all 8 N-slices of one M-tile share (L % 8) -> same XCD ->
    // A-tile fetched into that XCD's L2 once, reused 8x.
    const int L = blockIdx.x;
    const int m_low = L & 7;
    const int rest = L >> 3;          // 0..159
    const int n = rest & 7;           // 0..7
    const int m_high = rest >> 3;     // 0..19
    const int m = m_high * 8 + m_low; // 0..159
    const int tileM = m * 64, tileN = n * 64;

    const int t = threadIdx.x;
    const int lane = t & 63;
    const int wave = t >> 6;
    const int wm = wave >> 1, wn = wave & 1;
    const int quad = lane >> 4, r16 = lane & 15;

    floatx4 acc[2][2] = {};

    const unsigned short* ap[2];
#pragma unroll
    for (int q = 0; q < 2; ++q) {
        const int c = t + 256 * q;      // 0..511
        const int row = c >> 3;         // 0..63
        int g = tileM + row; if (g >= M) g = M - 1;
        ap[q] = A + (size_t)g * 512 + (((c & 7) ^ (row & 7)) * 8);
    }
    const unsigned short* bp[2];
#pragma unroll
    for (int q = 0; q < 2; ++q) {
        const int c = t + 256 * q;
        const int row = c >> 3;
        bp[q] = Bt + (size_t)(tileN + row) * 512 + (((c & 7) ^ (row & 7)) * 8);
    }

    for (int k0 = 0; k0 < 512; k0 += 64) {
        gl_lds16(ap[0] + k0, lsA + (size_t)t * 8);
        gl_lds16(ap[1] + k0, lsA + (size_t)(t + 256) * 8);
        gl_lds16(bp[0] + k0, lsB + (size_t)t * 8);
        gl_lds16(bp[1] + k0, lsB + (size_t)(t + 256) * 8);
        __syncthreads();

        short8 af[2][2], bfr[2][2];
#pragma unroll
        for (int i = 0; i < 2; ++i) {
            const int row = wm * 32 + i * 16 + r16;
#pragma unroll
            for (int kk = 0; kk < 2; ++kk) {
                const int kcw = kk * 4 + quad;
                af[i][kk] = *(const short8*)&lsA[(size_t)(row * 8 + (kcw ^ (row & 7))) * 8];
            }
        }
#pragma unroll
        for (int j = 0; j < 2; ++j) {
            const int row = wn * 32 + j * 16 + r16;
#pragma unroll
            for (int kk = 0; kk < 2; ++kk) {
                const int kcw = kk * 4 + quad;
                bfr[j][kk] = *(const short8*)&lsB[(size_t)(row * 8 + (kcw ^ (row & 7))) * 8];
            }
        }
#pragma unroll
        for (int kk = 0; kk < 2; ++kk)  // K ascending -> numerics identical to baseline
#pragma unroll
            for (int i = 0; i < 2; ++i)
#pragma unroll
                for (int j = 0; j < 2; ++j)
                    acc[i][j] = __builtin_amdgcn_mfma_f32_16x16x32_bf16(af[i][kk], bfr[j][kk], acc[i][j], 0, 0, 0);
        __syncthreads();
    }

    if (mode == 2) {
        float part[2][4] = {};
#pragma unroll
        for (int i = 0; i < 2; ++i) {
#pragma unroll
            for (int j = 0; j < 2; ++j) {
                const int col = tileN + wn * 32 + j * 16 + r16;
                const float bcol = bias[col];
                const float wcol = w2[col];
#pragma unroll
                for (int reg = 0; reg < 4; ++reg) {
                    float v = fmaxf(acc[i][j][reg] + bcol, 0.f);
                    part[i][reg] += v * wcol;
                }
            }
        }
#pragma unroll
        for (int off = 1; off <= 8; off <<= 1)
#pragma unroll
            for (int i = 0; i < 2; ++i)
#pragma unroll
                for (int reg = 0; reg < 4; ++reg)
                    part[i][reg] += __shfl_xor(part[i][reg], off, 64);
        if (r16 == 0) {
#pragma unroll
            for (int i = 0; i < 2; ++i)
#pragma unroll
                for (int reg = 0; reg < 4; ++reg) {
                    const int row = tileM + wm * 32 + i * 16 + quad * 4 + reg;
                    if (row < M) atomicAdd(&outp[row], part[i][reg]);
                }
        }
    } else {
#pragma unroll
        for (int i = 0; i < 2; ++i) {
#pragma unroll
            for (int j = 0; j < 2; ++j) {
                const int col = tileN + wn * 32 + j * 16 + r16;
#pragma unroll
                for (int reg = 0; reg < 4; ++reg) {
                    const int row = tileM + wm * 32 + i * 16 + quad * 4 + reg;
                    if (row < M) C[(size_t)row * 512 + col] = f2bf(acc[i][j][reg]);
                }
            }
        }
    }
}

// ---------- SpMM + bias + relu on fixed-capacity padded rows ----------
// r4: rounds of 4 (was 8). Average padded degree drops ~20 -> ~18 (-10%
// gather traffic, the dominant SpMM cost). Real-edge accumulation order is
// UNCHANGED (ascending edge index; pads are exact +0) -> numerics identical.
__global__ __launch_bounds__(256)
void spmm_pad(const int* __restrict__ fill, const int* __restrict__ cols,
              const float* __restrict__ vals, const unsigned short* __restrict__ hmat,
              const float* __restrict__ bias, unsigned short* __restrict__ xout) {
    const int wave = threadIdx.x >> 6, lane = threadIdx.x & 63;
    const int r = blockIdx.x * 4 + wave;
    if (r >= NNODES) return;
    int cnt = fill[r];
    cnt = __builtin_amdgcn_readfirstlane(cnt);   // wave-uniform by construction
    const int s = r * CAP;
    const int e = s + ((cnt + 3) & ~3);
    const int cb = lane * 8;
    float acc[8] = {0.f, 0.f, 0.f, 0.f, 0.f, 0.f, 0.f, 0.f};

    for (int i = s; i < e; i += 4) {
        int c[4]; float v[4]; short8 g[4];
#pragma unroll
        for (int u = 0; u < 4; ++u) { c[u] = cols[i + u]; v[u] = vals[i + u]; }
#pragma unroll
        for (int u = 0; u < 4; ++u) g[u] = *(const short8*)(hmat + (size_t)c[u] * H + cb);
#pragma unroll
        for (int u = 0; u < 4; ++u)  // real-edge order preserved; pads are exact +0
#pragma unroll
            for (int j = 0; j < 8; ++j) acc[j] += v[u] * bf2f((unsigned short)g[u][j]);
    }

    short8 o;
#pragma unroll
    for (int j = 0; j < 8; ++j)
        o[j] = (short)f2bf(fmaxf(acc[j] + bias[cb + j], 0.f));
    *(short8*)(xout + (size_t)r * H + cb) = o;
}

// ---------- tail: out[r] = sigmoid(out[r] + b2) in place ----------
__global__ __launch_bounds__(256)
void sigmoid_tail(float* __restrict__ out, const float* __restrict__ b2, int n) {
    int i = blockIdx.x * blockDim.x + threadIdx.x;
    if (i < n) out[i] = 1.f / (1.f + expf(-(out[i] + b2[0])));
}

extern "C" void kernel_launch(void* const* d_in, const int* in_sizes, int n_in,
                              void* d_out, int out_size, void* d_ws, size_t ws_size,
                              hipStream_t stream) {
    (void)in_sizes; (void)n_in; (void)out_size; (void)ws_size;
    const float* feat   = (const float*)d_in[0];
    const int* adj_row  = (const int*)d_in[1];
    const int* adj_col  = (const int*)d_in[2];
    const float* adj_val= (const float*)d_in[3];
    const float* Wg     = (const float*)d_in[4];
    const float* bg     = (const float*)d_in[5];
    const float* vw1    = (const float*)d_in[6];
    const float* vb1    = (const float*)d_in[7];
    const float* vw2    = (const float*)d_in[8];
    const float* vb2    = (const float*)d_in[9];
    float* out = (float*)d_out;

    // workspace layout (bytes)
    char* ws = (char*)d_ws;
    unsigned short* x  = (unsigned short*)(ws + 0);          // 10,240,000
    unsigned short* h  = (unsigned short*)(ws + 10240000);   // 10,240,000
    unsigned short* Wt = (unsigned short*)(ws + 20480000);   // 3,145,728
    int*   fill    = (int*)(ws + 23625728);                  // 40,000
    int*   colsP   = (int*)(ws + 23665728);                  // 2,560,000 (CAP*NNODES ints)
    float* valsP   = (float*)(ws + 26225728);                // 2,560,000 -> ~28.8 MB total
    // fill..valsP-end is one contiguous 5,160,000-byte region -> single zero pass.

    // --- prep (2 dispatches) ---
    prep_fused<<<ZB + CB + TB + OB, 256, 0, stream>>>(fill, feat, x, Wg, vw1, Wt, out);
    edge_scatter_direct<<<(NEDGES + 255) / 256, 256, 0, stream>>>(adj_row, adj_col, adj_val,
                                                                  fill, colsP, valsP, NEDGES);

    // --- layers ---
    for (int l = 0; l < NLAYERS; ++l) {
        gemm_bf16_xcd<<<1280, 256, 0, stream>>>(x, Wt + (size_t)l * H * H, h,
                                                nullptr, nullptr, nullptr, 0, NNODES);
        spmm_pad<<<(NNODES + 3) / 4, 256, 0, stream>>>(fill, colsP, valsP, h, bg + (size_t)l * H, x);
    }
    // head fused into the last GEMM epilogue (no h2 materialization)
    gemm_bf16_xcd<<<1280, 256, 0, stream>>>(x, Wt + (size_t)NLAYERS * H * H, nullptr,
                                            vb1, vw2, out, 2, NNODES);
    sigmoid_tail<<<(NNODES + 255) / 256, 256, 0, stream>>>(out, vb2, NNODES);
}